// Round 1
// baseline (715.197 us; speedup 1.0000x reference)
//
#include <hip/hip_runtime.h>

#define D_MODEL 2048
#define SEQ 2048
#define BATCH 2
#define NH 16
#define NKV 4
#define HD 128
#define KVD (NKV * HD)              // 512
#define QKVN (D_MODEL + 2 * KVD)    // 3072
#define MROWS (BATCH * SEQ)         // 4096

typedef __attribute__((ext_vector_type(8))) short short8;
typedef __attribute__((ext_vector_type(4))) float f32x4;

__device__ __forceinline__ unsigned short f2bf(float f) {
    union { float f; unsigned int u; } v; v.f = f;
    unsigned int r = (v.u + 0x7FFFu + ((v.u >> 16) & 1u)) >> 16;
    return (unsigned short)r;
}

__device__ __forceinline__ void async16(const void* g, void* l) {
    __builtin_amdgcn_global_load_lds((const __attribute__((address_space(1))) void*)g,
                                     (__attribute__((address_space(3))) void*)l, 16, 0, 0);
}

// ---------------- elementwise f32 -> bf16 cast (float4 vectorized) ----------------
__global__ __launch_bounds__(256) void cast_f2b(const float* __restrict__ in,
                                                unsigned short* __restrict__ out, int n4) {
    int i = blockIdx.x * 256 + threadIdx.x;
    if (i < n4) {
        float4 v = ((const float4*)in)[i];
        ushort4 o;
        o.x = f2bf(v.x); o.y = f2bf(v.y); o.z = f2bf(v.z); o.w = f2bf(v.w);
        ((ushort4*)out)[i] = o;
    }
}

// ---------------- GEMM: C[M,N] = A[M,K] * W[N,K]^T  (bf16 in, fp32 out) ----------------
// 128x128 tile, BK=32, 4 waves (2x2 of 64x64), global_load_lds staging (m97 pattern).
__global__ __launch_bounds__(256) void gemm_bt(const unsigned short* __restrict__ A,
                                               const unsigned short* __restrict__ W,
                                               float* __restrict__ C, int M, int N, int K) {
    __shared__ unsigned short As[128 * 32];   // 8 KB
    __shared__ unsigned short Bs[128 * 32];   // 8 KB
    const int tid  = threadIdx.x;
    const int lane = tid & 63;
    const int wave = tid >> 6;
    const int qm   = lane & 15;
    const int quad = lane >> 4;
    const int m0 = blockIdx.y * 128;
    const int n0 = blockIdx.x * 128;
    const int wm = (wave >> 1) * 64;
    const int wn = (wave & 1) * 64;

    f32x4 acc[4][4];
#pragma unroll
    for (int i = 0; i < 4; i++)
#pragma unroll
        for (int j = 0; j < 4; j++) acc[i][j] = (f32x4){0.f, 0.f, 0.f, 0.f};

    // staging: thread t covers LDS bytes [t*16, t*16+16) => row t/4, in-row byte (t%4)*16
    const int r1 = tid >> 2;
    const int c1 = (tid & 3) * 8;  // ushort offset within row
    const unsigned short* Ag = A + (size_t)(m0 + r1) * K + c1;
    const unsigned short* Wg = W + (size_t)(n0 + r1) * K + c1;
    unsigned short* AsW = &As[wave * 512];  // wave-uniform base (bytes: wave*1024)
    unsigned short* BsW = &Bs[wave * 512];

    for (int kt = 0; kt < K; kt += 32) {
        async16(Ag,                  AsW);
        async16(Ag + (size_t)64 * K, AsW + 2048);
        async16(Wg,                  BsW);
        async16(Wg + (size_t)64 * K, BsW + 2048);
        Ag += 32; Wg += 32;
        __syncthreads();
        short8 af[4], bfr[4];
#pragma unroll
        for (int mi = 0; mi < 4; mi++)
            af[mi] = *(const short8*)&As[(wm + mi * 16 + qm) * 32 + quad * 8];
#pragma unroll
        for (int ni = 0; ni < 4; ni++)
            bfr[ni] = *(const short8*)&Bs[(wn + ni * 16 + qm) * 32 + quad * 8];
#pragma unroll
        for (int mi = 0; mi < 4; mi++)
#pragma unroll
            for (int ni = 0; ni < 4; ni++)
                acc[mi][ni] = __builtin_amdgcn_mfma_f32_16x16x32_bf16(af[mi], bfr[ni], acc[mi][ni], 0, 0, 0);
        __syncthreads();
    }
    // epilogue: C/D layout col = lane&15, row = quad*4 + r
#pragma unroll
    for (int mi = 0; mi < 4; mi++) {
#pragma unroll
        for (int r = 0; r < 4; r++) {
            int row = m0 + wm + mi * 16 + quad * 4 + r;
            float* Crow = C + (size_t)row * N + n0 + wn + qm;
#pragma unroll
            for (int ni = 0; ni < 4; ni++) Crow[ni * 16] = acc[mi][ni][r];
        }
    }
}

// ---------------- postprocess: rmsnorm + rope + gain + attn-scale, write q/k bf16 ----------------
__global__ __launch_bounds__(256) void postproc(const float* __restrict__ qkvf,
                                                const float* __restrict__ gain,
                                                unsigned short* __restrict__ qb,
                                                unsigned short* __restrict__ kb) {
    const int m = blockIdx.x;          // 0..4095
    const int b = m >> 11;
    const int s = m & 2047;
    const int wave = threadIdx.x >> 6;
    const int lane = threadIdx.x & 63;
    const float* row = qkvf + (size_t)m * QKVN;
    // rope: lane l pairs dims (l, l+64); freq index = l
    float inv_freq = powf(10000.0f, -(float)lane * (1.0f / 64.0f));
    float ang = (float)s * inv_freq;
    float sn, cs;
    sincosf(ang, &sn, &cs);
    const float scale = 0.08838834764831845f;  // 1/sqrt(128)
    for (int u = wave; u < 20; u += 4) {       // 16 q heads + 4 k heads
        int off = (u < 16) ? (u * HD) : (D_MODEL + (u - 16) * HD);
        float x1 = row[off + lane];
        float x2 = row[off + 64 + lane];
        float ss = x1 * x1 + x2 * x2;
        ss += __shfl_xor(ss, 1);  ss += __shfl_xor(ss, 2);  ss += __shfl_xor(ss, 4);
        ss += __shfl_xor(ss, 8);  ss += __shfl_xor(ss, 16); ss += __shfl_xor(ss, 32);
        float rs = rsqrtf(ss * (1.0f / 128.0f) + 1.1920929e-07f);
        float a1 = x1 * rs, a2 = x2 * rs;
        float o1 = a1 * cs + a2 * sn;
        float o2 = -a1 * sn + a2 * cs;
        if (u < 16) {
            float g = gain[u] * scale;
            o1 *= g; o2 *= g;
            size_t base = ((size_t)(b * NH + u) * SEQ + s) * HD;
            qb[base + lane] = f2bf(o1);
            qb[base + 64 + lane] = f2bf(o2);
        } else {
            size_t base = ((size_t)(b * NKV + (u - 16)) * SEQ + s) * HD;
            kb[base + lane] = f2bf(o1);
            kb[base + 64 + lane] = f2bf(o2);
        }
    }
}

// ---------------- V transpose: qkv fp32 [m][2560+hk*128+d] -> vt bf16 [b][hk][d][s] ----------------
__global__ __launch_bounds__(256) void vtrans(const float* __restrict__ qkvf,
                                              unsigned short* __restrict__ vt) {
    __shared__ float tile[64][65];
    int idx = blockIdx.x;
    int st = idx & 31;
    int dt = (idx >> 5) & 1;
    int hk = (idx >> 6) & 3;
    int b  = idx >> 8;
    int t  = threadIdx.x;
    int cr = t >> 4;         // 0..15
    int cc = (t & 15) * 4;   // 0..60
#pragma unroll
    for (int j = 0; j < 4; j++) {
        int row = j * 16 + cr;  // s-local
        const float* src = qkvf + (size_t)(b * SEQ + st * 64 + row) * QKVN
                         + (D_MODEL + KVD) + hk * HD + dt * 64 + cc;
        float4 v = *(const float4*)src;
        tile[row][cc + 0] = v.x; tile[row][cc + 1] = v.y;
        tile[row][cc + 2] = v.z; tile[row][cc + 3] = v.w;
    }
    __syncthreads();
#pragma unroll
    for (int j = 0; j < 4; j++) {
        int drow = j * 16 + cr;  // d-local
        ushort4 ov;
        ov.x = f2bf(tile[cc + 0][drow]);
        ov.y = f2bf(tile[cc + 1][drow]);
        ov.z = f2bf(tile[cc + 2][drow]);
        ov.w = f2bf(tile[cc + 3][drow]);
        *(ushort4*)(vt + (size_t)((b * NKV + hk) * HD + dt * 64 + drow) * SEQ + st * 64 + cc) = ov;
    }
}

// ---------------- flash attention: one wave per 16 q rows, BKV=32, causal ----------------
__global__ __launch_bounds__(256) void attn(const unsigned short* __restrict__ qb,
                                            const unsigned short* __restrict__ kb,
                                            const unsigned short* __restrict__ vt,
                                            unsigned short* __restrict__ y) {
    __shared__ unsigned short plds[4][16 * 40];  // wave-private P buffer, padded rows
    const int lane = threadIdx.x & 63;
    const int wave = threadIdx.x >> 6;
    const int gw = blockIdx.x * 4 + wave;   // 0..4095
    const int qt = gw & 127;                // q tile (16 rows) within head
    const int bh = gw >> 7;                 // 0..31
    const int h  = bh & 15;
    const int b  = bh >> 4;
    const int qm   = lane & 15;
    const int quad = lane >> 4;
    const int qrow0 = qt * 16;

    const unsigned short* Qp = qb + (((size_t)(b * NH + h)) * SEQ + qrow0) * HD;
    const unsigned short* Kp = kb + ((size_t)(b * NKV + (h >> 2))) * SEQ * HD;
    const unsigned short* Vp = vt + ((size_t)(b * NKV + (h >> 2))) * HD * SEQ;

    // Q A-fragments (scale already folded into qb)
    short8 qf[4];
#pragma unroll
    for (int c = 0; c < 4; c++)
        qf[c] = *(const short8*)(Qp + qm * HD + c * 32 + quad * 8);

    f32x4 o[8];
#pragma unroll
    for (int t = 0; t < 8; t++) o[t] = (f32x4){0.f, 0.f, 0.f, 0.f};
    float mr[4], lr[4];
#pragma unroll
    for (int r = 0; r < 4; r++) { mr[r] = -3.0e38f; lr[r] = 0.f; }

    unsigned short* P = &plds[wave][0];
    const int ntiles = (qrow0 + 47) >> 5;

    for (int kt2 = 0; kt2 < ntiles; kt2++) {
        const int kv0 = kt2 * 32;
        f32x4 s0 = (f32x4){0.f, 0.f, 0.f, 0.f};
        f32x4 s1 = (f32x4){0.f, 0.f, 0.f, 0.f};
        const unsigned short* K0 = Kp + (size_t)(kv0 + qm) * HD;
        const unsigned short* K1 = K0 + 16 * HD;
#pragma unroll
        for (int c = 0; c < 4; c++) {
            short8 k0 = *(const short8*)(K0 + c * 32 + quad * 8);
            short8 k1 = *(const short8*)(K1 + c * 32 + quad * 8);
            s0 = __builtin_amdgcn_mfma_f32_16x16x32_bf16(qf[c], k0, s0, 0, 0, 0);
            s1 = __builtin_amdgcn_mfma_f32_16x16x32_bf16(qf[c], k1, s1, 0, 0, 0);
        }
        if (kv0 + 31 > qrow0) {  // tile touches the diagonal for some row
#pragma unroll
            for (int r = 0; r < 4; r++) {
                int qg = qrow0 + quad * 4 + r;
                if (kv0 + qm > qg)      s0[r] = -3.0e38f;
                if (kv0 + 16 + qm > qg) s1[r] = -3.0e38f;
            }
        }
        float p0[4], p1[4], alpha[4];
#pragma unroll
        for (int r = 0; r < 4; r++) {
            float mt = fmaxf(s0[r], s1[r]);
            mt = fmaxf(mt, __shfl_xor(mt, 1));
            mt = fmaxf(mt, __shfl_xor(mt, 2));
            mt = fmaxf(mt, __shfl_xor(mt, 4));
            mt = fmaxf(mt, __shfl_xor(mt, 8));
            float mn = fmaxf(mr[r], mt);
            alpha[r] = __expf(mr[r] - mn);
            mr[r] = mn;
            p0[r] = __expf(s0[r] - mn);
            p1[r] = __expf(s1[r] - mn);
            float rsum = p0[r] + p1[r];
            rsum += __shfl_xor(rsum, 1);
            rsum += __shfl_xor(rsum, 2);
            rsum += __shfl_xor(rsum, 4);
            rsum += __shfl_xor(rsum, 8);
            lr[r] = lr[r] * alpha[r] + rsum;
        }
#pragma unroll
        for (int t = 0; t < 8; t++)
#pragma unroll
            for (int r = 0; r < 4; r++) o[t][r] *= alpha[r];
        // P: C-layout -> A-layout via wave-private LDS (padded stride 40 ushorts)
#pragma unroll
        for (int r = 0; r < 4; r++) {
            P[(quad * 4 + r) * 40 + qm]      = f2bf(p0[r]);
            P[(quad * 4 + r) * 40 + 16 + qm] = f2bf(p1[r]);
        }
        short8 pa = *(const short8*)&P[qm * 40 + quad * 8];
#pragma unroll
        for (int t = 0; t < 8; t++) {
            short8 vf = *(const short8*)(Vp + (size_t)(t * 16 + qm) * SEQ + kv0 + quad * 8);
            o[t] = __builtin_amdgcn_mfma_f32_16x16x32_bf16(pa, vf, o[t], 0, 0, 0);
        }
    }
    float rl[4];
#pragma unroll
    for (int r = 0; r < 4; r++) rl[r] = 1.0f / lr[r];
#pragma unroll
    for (int t = 0; t < 8; t++) {
#pragma unroll
        for (int r = 0; r < 4; r++) {
            size_t row = (size_t)(b * SEQ + qrow0 + quad * 4 + r);
            y[row * D_MODEL + h * HD + t * 16 + qm] = f2bf(o[t][r] * rl[r]);
        }
    }
}

extern "C" void kernel_launch(void* const* d_in, const int* in_sizes, int n_in,
                              void* d_out, int out_size, void* d_ws, size_t ws_size,
                              hipStream_t stream) {
    const float* x  = (const float*)d_in[0];
    const float* Wq = (const float*)d_in[1];
    const float* Wk = (const float*)d_in[2];
    const float* Wv = (const float*)d_in[3];
    const float* Wp = (const float*)d_in[4];
    const float* qg = (const float*)d_in[5];

    char* ws = (char*)d_ws;
    unsigned short* xb   = (unsigned short*)(ws + 0);          // 16 MB (reused as y after GEMM1)
    unsigned short* wqkv = (unsigned short*)(ws + 16777216);   // 12 MB
    unsigned short* wp   = (unsigned short*)(ws + 29360128);   // 8 MB
    float*          qkvf = (float*)         (ws + 37748736);   // 48 MB
    unsigned short* qbuf = (unsigned short*)(ws + 88080384);   // 16 MB
    unsigned short* kbuf = (unsigned short*)(ws + 104857600);  // 4 MB
    unsigned short* vtb  = (unsigned short*)(ws + 109051904);  // 4 MB
    unsigned short* y    = xb;                                 // alias: xb dead after GEMM1

    cast_f2b<<<8192, 256, 0, stream>>>(x,  xb,   2097152);
    cast_f2b<<<4096, 256, 0, stream>>>(Wq, wqkv,           1048576);
    cast_f2b<<<1024, 256, 0, stream>>>(Wk, wqkv + 4194304,  262144);
    cast_f2b<<<1024, 256, 0, stream>>>(Wv, wqkv + 5242880,  262144);
    cast_f2b<<<4096, 256, 0, stream>>>(Wp, wp,             1048576);

    gemm_bt<<<dim3(24, 32), 256, 0, stream>>>(xb, wqkv, qkvf, MROWS, QKVN, D_MODEL);
    postproc<<<MROWS, 256, 0, stream>>>(qkvf, qg, qbuf, kbuf);
    vtrans<<<512, 256, 0, stream>>>(qkvf, vtb);
    attn<<<1024, 256, 0, stream>>>(qbuf, kbuf, vtb, y);
    gemm_bt<<<dim3(16, 32), 256, 0, stream>>>(y, wp, (float*)d_out, MROWS, D_MODEL, D_MODEL);
}

// Round 2
// 412.822 us; speedup vs baseline: 1.7325x; 1.7325x over previous
//
#include <hip/hip_runtime.h>

#define D_MODEL 2048
#define SEQ 2048
#define BATCH 2
#define NH 16
#define NKV 4
#define HD 128
#define KVD (NKV * HD)              // 512
#define QKVN (D_MODEL + 2 * KVD)    // 3072
#define MROWS (BATCH * SEQ)         // 4096

typedef __attribute__((ext_vector_type(8))) short short8;
typedef __attribute__((ext_vector_type(4))) float f32x4;

__device__ __forceinline__ unsigned short f2bf(float f) {
    union { float f; unsigned int u; } v; v.f = f;
    unsigned int r = (v.u + 0x7FFFu + ((v.u >> 16) & 1u)) >> 16;
    return (unsigned short)r;
}

__device__ __forceinline__ void async16(const void* g, void* l) {
    __builtin_amdgcn_global_load_lds((const __attribute__((address_space(1))) void*)g,
                                     (__attribute__((address_space(3))) void*)l, 16, 0, 0);
}

// ---------------- elementwise f32 -> bf16 cast (float4 vectorized) ----------------
__global__ __launch_bounds__(256) void cast_f2b(const float* __restrict__ in,
                                                unsigned short* __restrict__ out, int n4) {
    int i = blockIdx.x * 256 + threadIdx.x;
    if (i < n4) {
        float4 v = ((const float4*)in)[i];
        ushort4 o;
        o.x = f2bf(v.x); o.y = f2bf(v.y); o.z = f2bf(v.z); o.w = f2bf(v.w);
        ((ushort4*)out)[i] = o;
    }
}

// ---------------- GEMM: C[M,N] = A[M,K] * W[N,K]^T  (bf16 in, fp32 out) ----------------
// 128x128 tile, BK=32, 4 waves (2x2 of 64x64), global_load_lds staging (m97 pattern).
__global__ __launch_bounds__(256) void gemm_bt(const unsigned short* __restrict__ A,
                                               const unsigned short* __restrict__ W,
                                               float* __restrict__ C, int M, int N, int K) {
    __shared__ unsigned short As[128 * 32];   // 8 KB
    __shared__ unsigned short Bs[128 * 32];   // 8 KB
    const int tid  = threadIdx.x;
    const int lane = tid & 63;
    const int wave = tid >> 6;
    const int qm   = lane & 15;
    const int quad = lane >> 4;
    const int m0 = blockIdx.y * 128;
    const int n0 = blockIdx.x * 128;
    const int wm = (wave >> 1) * 64;
    const int wn = (wave & 1) * 64;

    f32x4 acc[4][4];
#pragma unroll
    for (int i = 0; i < 4; i++)
#pragma unroll
        for (int j = 0; j < 4; j++) acc[i][j] = (f32x4){0.f, 0.f, 0.f, 0.f};

    const int r1 = tid >> 2;
    const int c1 = (tid & 3) * 8;  // ushort offset within row
    const unsigned short* Ag = A + (size_t)(m0 + r1) * K + c1;
    const unsigned short* Wg = W + (size_t)(n0 + r1) * K + c1;
    unsigned short* AsW = &As[wave * 512];  // wave-uniform base (bytes: wave*1024)
    unsigned short* BsW = &Bs[wave * 512];

    for (int kt = 0; kt < K; kt += 32) {
        async16(Ag,                  AsW);
        async16(Ag + (size_t)64 * K, AsW + 2048);
        async16(Wg,                  BsW);
        async16(Wg + (size_t)64 * K, BsW + 2048);
        Ag += 32; Wg += 32;
        __syncthreads();
        short8 af[4], bfr[4];
#pragma unroll
        for (int mi = 0; mi < 4; mi++)
            af[mi] = *(const short8*)&As[(wm + mi * 16 + qm) * 32 + quad * 8];
#pragma unroll
        for (int ni = 0; ni < 4; ni++)
            bfr[ni] = *(const short8*)&Bs[(wn + ni * 16 + qm) * 32 + quad * 8];
#pragma unroll
        for (int mi = 0; mi < 4; mi++)
#pragma unroll
            for (int ni = 0; ni < 4; ni++)
                acc[mi][ni] = __builtin_amdgcn_mfma_f32_16x16x32_bf16(af[mi], bfr[ni], acc[mi][ni], 0, 0, 0);
        __syncthreads();
    }
#pragma unroll
    for (int mi = 0; mi < 4; mi++) {
#pragma unroll
        for (int r = 0; r < 4; r++) {
            int row = m0 + wm + mi * 16 + quad * 4 + r;
            float* Crow = C + (size_t)row * N + n0 + wn + qm;
#pragma unroll
            for (int ni = 0; ni < 4; ni++) Crow[ni * 16] = acc[mi][ni][r];
        }
    }
}

// ---------------- postprocess: rmsnorm + rope + gain + attn-scale, write q/k bf16 ----------------
__global__ __launch_bounds__(256) void postproc(const float* __restrict__ qkvf,
                                                const float* __restrict__ gain,
                                                unsigned short* __restrict__ qb,
                                                unsigned short* __restrict__ kb) {
    const int m = blockIdx.x;          // 0..4095
    const int b = m >> 11;
    const int s = m & 2047;
    const int wave = threadIdx.x >> 6;
    const int lane = threadIdx.x & 63;
    const float* row = qkvf + (size_t)m * QKVN;
    float inv_freq = powf(10000.0f, -(float)lane * (1.0f / 64.0f));
    float ang = (float)s * inv_freq;
    float sn, cs;
    sincosf(ang, &sn, &cs);
    const float scale = 0.08838834764831845f;  // 1/sqrt(128)
    for (int u = wave; u < 20; u += 4) {       // 16 q heads + 4 k heads
        int off = (u < 16) ? (u * HD) : (D_MODEL + (u - 16) * HD);
        float x1 = row[off + lane];
        float x2 = row[off + 64 + lane];
        float ss = x1 * x1 + x2 * x2;
        ss += __shfl_xor(ss, 1);  ss += __shfl_xor(ss, 2);  ss += __shfl_xor(ss, 4);
        ss += __shfl_xor(ss, 8);  ss += __shfl_xor(ss, 16); ss += __shfl_xor(ss, 32);
        float rs = rsqrtf(ss * (1.0f / 128.0f) + 1.1920929e-07f);
        float a1 = x1 * rs, a2 = x2 * rs;
        float o1 = a1 * cs + a2 * sn;
        float o2 = -a1 * sn + a2 * cs;
        if (u < 16) {
            float g = gain[u] * scale;
            o1 *= g; o2 *= g;
            size_t base = ((size_t)(b * NH + u) * SEQ + s) * HD;
            qb[base + lane] = f2bf(o1);
            qb[base + 64 + lane] = f2bf(o2);
        } else {
            size_t base = ((size_t)(b * NKV + (u - 16)) * SEQ + s) * HD;
            kb[base + lane] = f2bf(o1);
            kb[base + 64 + lane] = f2bf(o2);
        }
    }
}

// ---------------- V transpose: qkv fp32 -> vt bf16 [b][hk][d][s] ----------------
__global__ __launch_bounds__(256) void vtrans(const float* __restrict__ qkvf,
                                              unsigned short* __restrict__ vt) {
    __shared__ float tile[64][65];
    int idx = blockIdx.x;
    int st = idx & 31;
    int dt = (idx >> 5) & 1;
    int hk = (idx >> 6) & 3;
    int b  = idx >> 8;
    int t  = threadIdx.x;
    int cr = t >> 4;         // 0..15
    int cc = (t & 15) * 4;   // 0..60
#pragma unroll
    for (int j = 0; j < 4; j++) {
        int row = j * 16 + cr;  // s-local
        const float* src = qkvf + (size_t)(b * SEQ + st * 64 + row) * QKVN
                         + (D_MODEL + KVD) + hk * HD + dt * 64 + cc;
        float4 v = *(const float4*)src;
        tile[row][cc + 0] = v.x; tile[row][cc + 1] = v.y;
        tile[row][cc + 2] = v.z; tile[row][cc + 3] = v.w;
    }
    __syncthreads();
#pragma unroll
    for (int j = 0; j < 4; j++) {
        int drow = j * 16 + cr;  // d-local
        ushort4 ov;
        ov.x = f2bf(tile[cc + 0][drow]);
        ov.y = f2bf(tile[cc + 1][drow]);
        ov.z = f2bf(tile[cc + 2][drow]);
        ov.w = f2bf(tile[cc + 3][drow]);
        *(ushort4*)(vt + (size_t)((b * NKV + hk) * HD + dt * 64 + drow) * SEQ + st * 64 + cc) = ov;
    }
}

// ---------------- flash attention v2: block-cooperative LDS staging ----------------
// Block = 4 waves = 64 q-rows of one (b,h). Per 32-row KV tile: stage K(32x128) and
// V^T(128x32) into LDS (global_load_lds w16, coalesced, shared x4 waves), fragments
// via ds_read_b128. Grid: bh = blockIdx&31 (XCD spread), qt64 = blockIdx>>5 (balance).
__global__ __launch_bounds__(256, 4) void attn(const unsigned short* __restrict__ qb,
                                               const unsigned short* __restrict__ kb,
                                               const unsigned short* __restrict__ vt,
                                               unsigned short* __restrict__ y) {
    __shared__ unsigned short Ks[4096];      // [c][r][j]: c*1024 + r*32 + j (8 KB)
    __shared__ unsigned short Vs[4096];      // [d][s]:    d*32 + s         (8 KB)
    __shared__ unsigned short plds[4][640];  // wave-private P, 16 rows x 40 (padded)
    const int tid  = threadIdx.x;
    const int lane = tid & 63;
    const int wave = tid >> 6;
    const int bh   = blockIdx.x & 31;
    const int qt64 = blockIdx.x >> 5;
    const int h = bh & 15;
    const int b = bh >> 4;
    const int qm   = lane & 15;
    const int quad = lane >> 4;
    const int q0    = qt64 * 64;
    const int qrow0 = q0 + wave * 16;

    const unsigned short* Qp = qb + (((size_t)(b * NH + h)) * SEQ + qrow0) * HD;
    const unsigned short* Kp = kb + ((size_t)(b * NKV + (h >> 2))) * SEQ * HD;
    const unsigned short* Vp = vt + ((size_t)(b * NKV + (h >> 2))) * HD * SEQ;

    short8 qf[4];
#pragma unroll
    for (int c = 0; c < 4; c++)
        qf[c] = *(const short8*)(Qp + qm * HD + c * 32 + quad * 8);

    f32x4 o[8];
#pragma unroll
    for (int t = 0; t < 8; t++) o[t] = (f32x4){0.f, 0.f, 0.f, 0.f};
    float mr[4], lr[4];
#pragma unroll
    for (int r = 0; r < 4; r++) { mr[r] = -3.0e38f; lr[r] = 0.f; }

    // staging addresses: thread t covers LDS ushorts [t*8, t*8+8) per issue
    const int sr = (tid & 127) >> 2;         // K row (issue covers rows 0..31)
    const int sj = (tid & 3) * 8;            // in-chunk col
    const unsigned short* KsA = Kp + sr * HD + (tid >> 7) * 32 + sj;       // chunks 0,1
    const unsigned short* VsA = Vp + (size_t)(tid >> 2) * SEQ + sj;        // d = tid>>2
    char* KsB = (char*)Ks + wave * 1024;
    char* VsB = (char*)Vs + wave * 1024;
    unsigned short* P = &plds[wave][0];

    const int kvend = q0 + 64;
    for (int kv0 = 0; kv0 < kvend; kv0 += 32) {
        async16(KsA,            KsB);
        async16(KsA + 64,       KsB + 4096);   // chunks 2,3
        async16(VsA,            VsB);
        async16(VsA + 64 * SEQ, VsB + 4096);   // d += 64
        KsA += 32 * HD;
        VsA += 32;
        __syncthreads();
        if (kv0 <= qrow0 + 15) {   // wave-uniform: skip fully-masked tiles
            f32x4 s0 = (f32x4){0.f, 0.f, 0.f, 0.f};
            f32x4 s1 = (f32x4){0.f, 0.f, 0.f, 0.f};
#pragma unroll
            for (int c = 0; c < 4; c++) {
                short8 k0 = *(const short8*)&Ks[c * 1024 + qm * 32 + quad * 8];
                short8 k1 = *(const short8*)&Ks[c * 1024 + (16 + qm) * 32 + quad * 8];
                s0 = __builtin_amdgcn_mfma_f32_16x16x32_bf16(qf[c], k0, s0, 0, 0, 0);
                s1 = __builtin_amdgcn_mfma_f32_16x16x32_bf16(qf[c], k1, s1, 0, 0, 0);
            }
            if (kv0 + 31 > qrow0) {
#pragma unroll
                for (int r = 0; r < 4; r++) {
                    int qg = qrow0 + quad * 4 + r;
                    if (kv0 + qm > qg)      s0[r] = -3.0e38f;
                    if (kv0 + 16 + qm > qg) s1[r] = -3.0e38f;
                }
            }
            float p0[4], p1[4], alpha[4];
#pragma unroll
            for (int r = 0; r < 4; r++) {
                float mt = fmaxf(s0[r], s1[r]);
                mt = fmaxf(mt, __shfl_xor(mt, 1));
                mt = fmaxf(mt, __shfl_xor(mt, 2));
                mt = fmaxf(mt, __shfl_xor(mt, 4));
                mt = fmaxf(mt, __shfl_xor(mt, 8));
                float mn = fmaxf(mr[r], mt);
                alpha[r] = __expf(mr[r] - mn);
                mr[r] = mn;
                p0[r] = __expf(s0[r] - mn);
                p1[r] = __expf(s1[r] - mn);
                float rsum = p0[r] + p1[r];
                rsum += __shfl_xor(rsum, 1);
                rsum += __shfl_xor(rsum, 2);
                rsum += __shfl_xor(rsum, 4);
                rsum += __shfl_xor(rsum, 8);
                lr[r] = lr[r] * alpha[r] + rsum;
            }
#pragma unroll
            for (int t = 0; t < 8; t++)
#pragma unroll
                for (int r = 0; r < 4; r++) o[t][r] *= alpha[r];
#pragma unroll
            for (int r = 0; r < 4; r++) {
                P[(quad * 4 + r) * 40 + qm]      = f2bf(p0[r]);
                P[(quad * 4 + r) * 40 + 16 + qm] = f2bf(p1[r]);
            }
            short8 pa = *(const short8*)&P[qm * 40 + quad * 8];
#pragma unroll
            for (int t = 0; t < 8; t++) {
                short8 vf = *(const short8*)&Vs[(t * 16 + qm) * 32 + quad * 8];
                o[t] = __builtin_amdgcn_mfma_f32_16x16x32_bf16(pa, vf, o[t], 0, 0, 0);
            }
        }
        __syncthreads();
    }
    float rl[4];
#pragma unroll
    for (int r = 0; r < 4; r++) rl[r] = 1.0f / lr[r];
#pragma unroll
    for (int t = 0; t < 8; t++) {
#pragma unroll
        for (int r = 0; r < 4; r++) {
            size_t row = (size_t)(b * SEQ + qrow0 + quad * 4 + r);
            y[row * D_MODEL + h * HD + t * 16 + qm] = f2bf(o[t][r] * rl[r]);
        }
    }
}

extern "C" void kernel_launch(void* const* d_in, const int* in_sizes, int n_in,
                              void* d_out, int out_size, void* d_ws, size_t ws_size,
                              hipStream_t stream) {
    const float* x  = (const float*)d_in[0];
    const float* Wq = (const float*)d_in[1];
    const float* Wk = (const float*)d_in[2];
    const float* Wv = (const float*)d_in[3];
    const float* Wp = (const float*)d_in[4];
    const float* qg = (const float*)d_in[5];

    char* ws = (char*)d_ws;
    unsigned short* xb   = (unsigned short*)(ws + 0);          // 16 MB (reused as y after GEMM1)
    unsigned short* wqkv = (unsigned short*)(ws + 16777216);   // 12 MB
    unsigned short* wp   = (unsigned short*)(ws + 29360128);   // 8 MB
    float*          qkvf = (float*)         (ws + 37748736);   // 48 MB
    unsigned short* qbuf = (unsigned short*)(ws + 88080384);   // 16 MB
    unsigned short* kbuf = (unsigned short*)(ws + 104857600);  // 4 MB
    unsigned short* vtb  = (unsigned short*)(ws + 109051904);  // 4 MB
    unsigned short* y    = xb;                                 // alias: xb dead after GEMM1

    cast_f2b<<<8192, 256, 0, stream>>>(x,  xb,   2097152);
    cast_f2b<<<4096, 256, 0, stream>>>(Wq, wqkv,           1048576);
    cast_f2b<<<1024, 256, 0, stream>>>(Wk, wqkv + 4194304,  262144);
    cast_f2b<<<1024, 256, 0, stream>>>(Wv, wqkv + 5242880,  262144);
    cast_f2b<<<4096, 256, 0, stream>>>(Wp, wp,             1048576);

    gemm_bt<<<dim3(24, 32), 256, 0, stream>>>(xb, wqkv, qkvf, MROWS, QKVN, D_MODEL);
    postproc<<<MROWS, 256, 0, stream>>>(qkvf, qg, qbuf, kbuf);
    vtrans<<<512, 256, 0, stream>>>(qkvf, vtb);
    attn<<<1024, 256, 0, stream>>>(qbuf, kbuf, vtb, y);
    gemm_bt<<<dim3(16, 32), 256, 0, stream>>>(y, wp, (float*)d_out, MROWS, D_MODEL, D_MODEL);
}

// Round 3
// 379.492 us; speedup vs baseline: 1.8846x; 1.0878x over previous
//
#include <hip/hip_runtime.h>

#define D_MODEL 2048
#define SEQ 2048
#define BATCH 2
#define NH 16
#define NKV 4
#define HD 128
#define KVD (NKV * HD)              // 512
#define QKVN (D_MODEL + 2 * KVD)    // 3072
#define MROWS (BATCH * SEQ)         // 4096

typedef __attribute__((ext_vector_type(8))) short short8;
typedef __attribute__((ext_vector_type(4))) float f32x4;

__device__ __forceinline__ unsigned short f2bf(float f) {
    union { float f; unsigned int u; } v; v.f = f;
    unsigned int r = (v.u + 0x7FFFu + ((v.u >> 16) & 1u)) >> 16;
    return (unsigned short)r;
}

// round-to-nearest for NON-NEGATIVE floats only (2 ops)
__device__ __forceinline__ unsigned short f2bf_pos(float f) {
    union { float f; unsigned int u; } v; v.f = f;
    return (unsigned short)((v.u + 0x8000u) >> 16);
}

__device__ __forceinline__ void async16(const void* g, void* l) {
    __builtin_amdgcn_global_load_lds((const __attribute__((address_space(1))) void*)g,
                                     (__attribute__((address_space(3))) void*)l, 16, 0, 0);
}

// ---------------- elementwise f32 -> bf16 cast (float4 vectorized) ----------------
__global__ __launch_bounds__(256) void cast_f2b(const float* __restrict__ in,
                                                unsigned short* __restrict__ out, int n4) {
    int i = blockIdx.x * 256 + threadIdx.x;
    if (i < n4) {
        float4 v = ((const float4*)in)[i];
        ushort4 o;
        o.x = f2bf(v.x); o.y = f2bf(v.y); o.z = f2bf(v.z); o.w = f2bf(v.w);
        ((ushort4*)out)[i] = o;
    }
}

// ---------------- GEMM: C[M,N] = A[M,K] * W[N,K]^T  (bf16 in, fp32 out) ----------------
// 128x128 tile, BK=32, 4 waves (2x2 of 64x64), global_load_lds staging (m97 pattern)
// + XOR chunk swizzle to kill the 8-way LDS bank conflict on fragment reads.
__global__ __launch_bounds__(256) void gemm_bt(const unsigned short* __restrict__ A,
                                               const unsigned short* __restrict__ W,
                                               float* __restrict__ C, int M, int N, int K) {
    __shared__ unsigned short As[128 * 32];   // 8 KB
    __shared__ unsigned short Bs[128 * 32];   // 8 KB
    const int tid  = threadIdx.x;
    const int lane = tid & 63;
    const int wave = tid >> 6;
    const int qm   = lane & 15;
    const int quad = lane >> 4;
    const int m0 = blockIdx.y * 128;
    const int n0 = blockIdx.x * 128;
    const int wm = (wave >> 1) * 64;
    const int wn = (wave & 1) * 64;

    f32x4 acc[4][4];
#pragma unroll
    for (int i = 0; i < 4; i++)
#pragma unroll
        for (int j = 0; j < 4; j++) acc[i][j] = (f32x4){0.f, 0.f, 0.f, 0.f};

    // staging: thread covers LDS row r1, swizzled 16B chunk (tid&3)^((r1>>1)&3)
    const int r1 = tid >> 2;
    const int c1 = (((tid & 3) ^ ((r1 >> 1) & 3)) * 8);
    const unsigned short* Ag = A + (size_t)(m0 + r1) * K + c1;
    const unsigned short* Wg = W + (size_t)(n0 + r1) * K + c1;
    unsigned short* AsW = &As[wave * 512];
    unsigned short* BsW = &Bs[wave * 512];
    const int swq = ((qm >> 1) & 3) * 8;  // read-side swizzle (uniform over mi/ni)

    for (int kt = 0; kt < K; kt += 32) {
        async16(Ag,                  AsW);
        async16(Ag + (size_t)64 * K, AsW + 2048);
        async16(Wg,                  BsW);
        async16(Wg + (size_t)64 * K, BsW + 2048);
        Ag += 32; Wg += 32;
        __syncthreads();
        short8 af[4], bfr[4];
#pragma unroll
        for (int mi = 0; mi < 4; mi++)
            af[mi] = *(const short8*)&As[(wm + mi * 16 + qm) * 32 + (quad * 8 ^ swq)];
#pragma unroll
        for (int ni = 0; ni < 4; ni++)
            bfr[ni] = *(const short8*)&Bs[(wn + ni * 16 + qm) * 32 + (quad * 8 ^ swq)];
#pragma unroll
        for (int mi = 0; mi < 4; mi++)
#pragma unroll
            for (int ni = 0; ni < 4; ni++)
                acc[mi][ni] = __builtin_amdgcn_mfma_f32_16x16x32_bf16(af[mi], bfr[ni], acc[mi][ni], 0, 0, 0);
        __syncthreads();
    }
#pragma unroll
    for (int mi = 0; mi < 4; mi++) {
#pragma unroll
        for (int r = 0; r < 4; r++) {
            int row = m0 + wm + mi * 16 + quad * 4 + r;
            float* Crow = C + (size_t)row * N + n0 + wn + qm;
#pragma unroll
            for (int ni = 0; ni < 4; ni++) Crow[ni * 16] = acc[mi][ni][r];
        }
    }
}

// ---------------- postprocess: rmsnorm + rope + gain + attn-scale, write q/k bf16 ----------------
// q pre-scale includes log2(e) so attention softmax can use exp2 directly.
__global__ __launch_bounds__(256) void postproc(const float* __restrict__ qkvf,
                                                const float* __restrict__ gain,
                                                unsigned short* __restrict__ qb,
                                                unsigned short* __restrict__ kb) {
    const int m = blockIdx.x;          // 0..4095
    const int b = m >> 11;
    const int s = m & 2047;
    const int wave = threadIdx.x >> 6;
    const int lane = threadIdx.x & 63;
    const float* row = qkvf + (size_t)m * QKVN;
    float inv_freq = powf(10000.0f, -(float)lane * (1.0f / 64.0f));
    float ang = (float)s * inv_freq;
    float sn, cs;
    sincosf(ang, &sn, &cs);
    const float scale = 0.12751744f;   // (1/sqrt(128)) * log2(e)
    for (int u = wave; u < 20; u += 4) {       // 16 q heads + 4 k heads
        int off = (u < 16) ? (u * HD) : (D_MODEL + (u - 16) * HD);
        float x1 = row[off + lane];
        float x2 = row[off + 64 + lane];
        float ss = x1 * x1 + x2 * x2;
        ss += __shfl_xor(ss, 1);  ss += __shfl_xor(ss, 2);  ss += __shfl_xor(ss, 4);
        ss += __shfl_xor(ss, 8);  ss += __shfl_xor(ss, 16); ss += __shfl_xor(ss, 32);
        float rs = rsqrtf(ss * (1.0f / 128.0f) + 1.1920929e-07f);
        float a1 = x1 * rs, a2 = x2 * rs;
        float o1 = a1 * cs + a2 * sn;
        float o2 = -a1 * sn + a2 * cs;
        if (u < 16) {
            float g = gain[u] * scale;
            o1 *= g; o2 *= g;
            size_t base = ((size_t)(b * NH + u) * SEQ + s) * HD;
            qb[base + lane] = f2bf(o1);
            qb[base + 64 + lane] = f2bf(o2);
        } else {
            size_t base = ((size_t)(b * NKV + (u - 16)) * SEQ + s) * HD;
            kb[base + lane] = f2bf(o1);
            kb[base + 64 + lane] = f2bf(o2);
        }
    }
}

// ---------------- V transpose: qkv fp32 -> vt bf16 [b][hk][d][s] ----------------
__global__ __launch_bounds__(256) void vtrans(const float* __restrict__ qkvf,
                                              unsigned short* __restrict__ vt) {
    __shared__ float tile[64][65];
    int idx = blockIdx.x;
    int st = idx & 31;
    int dt = (idx >> 5) & 1;
    int hk = (idx >> 6) & 3;
    int b  = idx >> 8;
    int t  = threadIdx.x;
    int cr = t >> 4;         // 0..15
    int cc = (t & 15) * 4;   // 0..60
#pragma unroll
    for (int j = 0; j < 4; j++) {
        int row = j * 16 + cr;  // s-local
        const float* src = qkvf + (size_t)(b * SEQ + st * 64 + row) * QKVN
                         + (D_MODEL + KVD) + hk * HD + dt * 64 + cc;
        float4 v = *(const float4*)src;
        tile[row][cc + 0] = v.x; tile[row][cc + 1] = v.y;
        tile[row][cc + 2] = v.z; tile[row][cc + 3] = v.w;
    }
    __syncthreads();
#pragma unroll
    for (int j = 0; j < 4; j++) {
        int drow = j * 16 + cr;  // d-local
        ushort4 ov;
        ov.x = f2bf(tile[cc + 0][drow]);
        ov.y = f2bf(tile[cc + 1][drow]);
        ov.z = f2bf(tile[cc + 2][drow]);
        ov.w = f2bf(tile[cc + 3][drow]);
        *(ushort4*)(vt + (size_t)((b * NKV + hk) * HD + dt * 64 + drow) * SEQ + st * 64 + cc) = ov;
    }
}

// ---------------- flash attention v3: swizzled LDS + exp2 softmax + balanced grid ----
__global__ __launch_bounds__(256, 4) void attn(const unsigned short* __restrict__ qb,
                                               const unsigned short* __restrict__ kb,
                                               const unsigned short* __restrict__ vt,
                                               unsigned short* __restrict__ y) {
    __shared__ unsigned short Ks[4096];      // [c][r][j^swz(r)] (8 KB)
    __shared__ unsigned short Vs[4096];      // [d][s^swz(d)]   (8 KB)
    __shared__ unsigned short plds[4][640];  // wave-private P, 16 rows x 40 (padded)
    const int tid  = threadIdx.x;
    const int lane = tid & 63;
    const int wave = tid >> 6;
    const int bh   = blockIdx.x & 31;
    // balanced qt64 map: each CU's 4 resident blocks sum to constant work
    const int g  = blockIdx.x >> 5;
    const int gg = g & 7;
    const int gs = g >> 3;
    const int qt64 = (gs == 0) ? gg : (gs == 1) ? (31 - gg) : (gs == 2) ? (8 + gg) : (23 - gg);
    const int h = bh & 15;
    const int b = bh >> 4;
    const int qm   = lane & 15;
    const int quad = lane >> 4;
    const int q0    = qt64 * 64;
    const int qrow0 = q0 + wave * 16;

    const unsigned short* Qp = qb + (((size_t)(b * NH + h)) * SEQ + qrow0) * HD;
    const unsigned short* Kp = kb + ((size_t)(b * NKV + (h >> 2))) * SEQ * HD;
    const unsigned short* Vp = vt + ((size_t)(b * NKV + (h >> 2))) * HD * SEQ;

    short8 qf[4];
#pragma unroll
    for (int c = 0; c < 4; c++)
        qf[c] = *(const short8*)(Qp + qm * HD + c * 32 + quad * 8);

    f32x4 o[8];
#pragma unroll
    for (int t = 0; t < 8; t++) o[t] = (f32x4){0.f, 0.f, 0.f, 0.f};
    float mr[4], lr[4];
#pragma unroll
    for (int r = 0; r < 4; r++) { mr[r] = -3.0e38f; lr[r] = 0.f; }

    // staging: thread t -> LDS chunk at linear pos; global chunk XOR-swizzled by row
    const int sr  = (tid & 127) >> 2;                        // K row 0..31
    const int skc = ((tid & 3) ^ ((sr >> 1) & 3)) * 8;       // K swizzled in-row col
    const unsigned short* KsA = Kp + sr * HD + (tid >> 7) * 32 + skc;
    const int vd  = tid >> 2;                                // V d-row 0..63
    const int svc = ((tid & 3) ^ ((vd >> 1) & 3)) * 8;       // V swizzled in-row col
    const unsigned short* VsA = Vp + (size_t)vd * SEQ + svc;
    char* KsB = (char*)Ks + wave * 1024;
    char* VsB = (char*)Vs + wave * 1024;
    unsigned short* P = &plds[wave][0];
    const int swq = ((qm >> 1) & 3) * 8;                     // read-side swizzle

    const int kvend = q0 + 64;
    for (int kv0 = 0; kv0 < kvend; kv0 += 32) {
        async16(KsA,            KsB);
        async16(KsA + 64,       KsB + 4096);   // chunks 2,3
        async16(VsA,            VsB);
        async16(VsA + 64 * SEQ, VsB + 4096);   // d += 64
        KsA += 32 * HD;
        VsA += 32;
        __syncthreads();
        if (kv0 <= qrow0 + 15) {   // wave-uniform: skip fully-masked tiles
            f32x4 s0 = (f32x4){0.f, 0.f, 0.f, 0.f};
            f32x4 s1 = (f32x4){0.f, 0.f, 0.f, 0.f};
#pragma unroll
            for (int c = 0; c < 4; c++) {
                short8 k0 = *(const short8*)&Ks[c * 1024 + qm * 32 + (quad * 8 ^ swq)];
                short8 k1 = *(const short8*)&Ks[c * 1024 + (16 + qm) * 32 + (quad * 8 ^ swq)];
                s0 = __builtin_amdgcn_mfma_f32_16x16x32_bf16(qf[c], k0, s0, 0, 0, 0);
                s1 = __builtin_amdgcn_mfma_f32_16x16x32_bf16(qf[c], k1, s1, 0, 0, 0);
            }
            if (kv0 + 31 > qrow0) {
#pragma unroll
                for (int r = 0; r < 4; r++) {
                    int qg = qrow0 + quad * 4 + r;
                    if (kv0 + qm > qg)      s0[r] = -3.0e38f;
                    if (kv0 + 16 + qm > qg) s1[r] = -3.0e38f;
                }
            }
            float p0[4], p1[4], alpha[4];
#pragma unroll
            for (int r = 0; r < 4; r++) {
                float mt = fmaxf(s0[r], s1[r]);
                mt = fmaxf(mt, __shfl_xor(mt, 1));
                mt = fmaxf(mt, __shfl_xor(mt, 2));
                mt = fmaxf(mt, __shfl_xor(mt, 4));
                mt = fmaxf(mt, __shfl_xor(mt, 8));
                float mn = fmaxf(mr[r], mt);
                alpha[r] = __builtin_amdgcn_exp2f(mr[r] - mn);   // log2-domain scores
                mr[r] = mn;
                p0[r] = __builtin_amdgcn_exp2f(s0[r] - mn);
                p1[r] = __builtin_amdgcn_exp2f(s1[r] - mn);
                float rsum = p0[r] + p1[r];
                rsum += __shfl_xor(rsum, 1);
                rsum += __shfl_xor(rsum, 2);
                rsum += __shfl_xor(rsum, 4);
                rsum += __shfl_xor(rsum, 8);
                lr[r] = lr[r] * alpha[r] + rsum;
            }
#pragma unroll
            for (int t = 0; t < 8; t++)
#pragma unroll
                for (int r = 0; r < 4; r++) o[t][r] *= alpha[r];
#pragma unroll
            for (int r = 0; r < 4; r++) {
                P[(quad * 4 + r) * 40 + qm]      = f2bf_pos(p0[r]);
                P[(quad * 4 + r) * 40 + 16 + qm] = f2bf_pos(p1[r]);
            }
            short8 pa = *(const short8*)&P[qm * 40 + quad * 8];
#pragma unroll
            for (int t = 0; t < 8; t++) {
                short8 vf = *(const short8*)&Vs[(t * 16 + qm) * 32 + (quad * 8 ^ swq)];
                o[t] = __builtin_amdgcn_mfma_f32_16x16x32_bf16(pa, vf, o[t], 0, 0, 0);
            }
        }
        __syncthreads();
    }
    float rl[4];
#pragma unroll
    for (int r = 0; r < 4; r++) rl[r] = 1.0f / lr[r];
#pragma unroll
    for (int t = 0; t < 8; t++) {
#pragma unroll
        for (int r = 0; r < 4; r++) {
            size_t row = (size_t)(b * SEQ + qrow0 + quad * 4 + r);
            y[row * D_MODEL + h * HD + t * 16 + qm] = f2bf(o[t][r] * rl[r]);
        }
    }
}

extern "C" void kernel_launch(void* const* d_in, const int* in_sizes, int n_in,
                              void* d_out, int out_size, void* d_ws, size_t ws_size,
                              hipStream_t stream) {
    const float* x  = (const float*)d_in[0];
    const float* Wq = (const float*)d_in[1];
    const float* Wk = (const float*)d_in[2];
    const float* Wv = (const float*)d_in[3];
    const float* Wp = (const float*)d_in[4];
    const float* qg = (const float*)d_in[5];

    char* ws = (char*)d_ws;
    unsigned short* xb   = (unsigned short*)(ws + 0);          // 16 MB (reused as y after GEMM1)
    unsigned short* wqkv = (unsigned short*)(ws + 16777216);   // 12 MB
    unsigned short* wp   = (unsigned short*)(ws + 29360128);   // 8 MB
    float*          qkvf = (float*)         (ws + 37748736);   // 48 MB
    unsigned short* qbuf = (unsigned short*)(ws + 88080384);   // 16 MB
    unsigned short* kbuf = (unsigned short*)(ws + 104857600);  // 4 MB
    unsigned short* vtb  = (unsigned short*)(ws + 109051904);  // 4 MB
    unsigned short* y    = xb;                                 // alias: xb dead after GEMM1

    cast_f2b<<<8192, 256, 0, stream>>>(x,  xb,   2097152);
    cast_f2b<<<4096, 256, 0, stream>>>(Wq, wqkv,           1048576);
    cast_f2b<<<1024, 256, 0, stream>>>(Wk, wqkv + 4194304,  262144);
    cast_f2b<<<1024, 256, 0, stream>>>(Wv, wqkv + 5242880,  262144);
    cast_f2b<<<4096, 256, 0, stream>>>(Wp, wp,             1048576);

    gemm_bt<<<dim3(24, 32), 256, 0, stream>>>(xb, wqkv, qkvf, MROWS, QKVN, D_MODEL);
    postproc<<<MROWS, 256, 0, stream>>>(qkvf, qg, qbuf, kbuf);
    vtrans<<<512, 256, 0, stream>>>(qkvf, vtb);
    attn<<<1024, 256, 0, stream>>>(qbuf, kbuf, vtb, y);
    gemm_bt<<<dim3(16, 32), 256, 0, stream>>>(y, wp, (float*)d_out, MROWS, D_MODEL, D_MODEL);
}

// Round 4
// 318.998 us; speedup vs baseline: 2.2420x; 1.1896x over previous
//
#include <hip/hip_runtime.h>

#define D_MODEL 2048
#define SEQ 2048
#define BATCH 2
#define NH 16
#define NKV 4
#define HD 128
#define KVD (NKV * HD)              // 512
#define QKVN (D_MODEL + 2 * KVD)    // 3072
#define MROWS (BATCH * SEQ)         // 4096

typedef __attribute__((ext_vector_type(8))) short short8;
typedef __attribute__((ext_vector_type(4))) float f32x4;

__device__ __forceinline__ unsigned short f2bf(float f) {
    union { float f; unsigned int u; } v; v.f = f;
    unsigned int r = (v.u + 0x7FFFu + ((v.u >> 16) & 1u)) >> 16;
    return (unsigned short)r;
}

// round-to-nearest for NON-NEGATIVE floats only (2 ops)
__device__ __forceinline__ unsigned short f2bf_pos(float f) {
    union { float f; unsigned int u; } v; v.f = f;
    return (unsigned short)((v.u + 0x8000u) >> 16);
}

__device__ __forceinline__ float bf2f(unsigned short u) {
    union { float f; unsigned int i; } v; v.i = ((unsigned int)u) << 16;
    return v.f;
}

__device__ __forceinline__ void async16(const void* g, void* l) {
    __builtin_amdgcn_global_load_lds((const __attribute__((address_space(1))) void*)g,
                                     (__attribute__((address_space(3))) void*)l, 16, 0, 0);
}

// ---------------- merged f32 -> bf16 cast for x, Wq, Wk, Wv, Wp (one launch) ----------
__global__ __launch_bounds__(256) void cast_all(const float* __restrict__ x,
                                                const float* __restrict__ wq,
                                                const float* __restrict__ wk,
                                                const float* __restrict__ wv,
                                                const float* __restrict__ wp,
                                                unsigned short* __restrict__ xb,
                                                unsigned short* __restrict__ wqkv,
                                                unsigned short* __restrict__ wpb) {
    int i = blockIdx.x * 256 + threadIdx.x;  // float4 index, regions block-aligned
    const float4* s; ushort4* d; int j;
    if (i < 2097152)      { s = (const float4*)x;  d = (ushort4*)xb;             j = i; }
    else if (i < 3145728) { s = (const float4*)wq; d = (ushort4*)wqkv;           j = i - 2097152; }
    else if (i < 3407872) { s = (const float4*)wk; d = (ushort4*)wqkv + 1048576; j = i - 3145728; }
    else if (i < 3670016) { s = (const float4*)wv; d = (ushort4*)wqkv + 1310720; j = i - 3407872; }
    else                  { s = (const float4*)wp; d = (ushort4*)wpb;            j = i - 3670016; }
    float4 v = s[j];
    ushort4 o;
    o.x = f2bf(v.x); o.y = f2bf(v.y); o.z = f2bf(v.z); o.w = f2bf(v.w);
    d[j] = o;
}

// ---------------- GEMM: C[M,N] = A[M,K] * W[N,K]^T  (bf16 in, fp32 or bf16 out) -------
// 128x128 tile, BK=32, 4 waves (2x2 of 64x64), global_load_lds staging + XOR swizzle.
template <bool BF16OUT>
__global__ __launch_bounds__(256) void gemm_bt(const unsigned short* __restrict__ A,
                                               const unsigned short* __restrict__ W,
                                               void* __restrict__ Cv, int M, int N, int K) {
    __shared__ unsigned short As[128 * 32];   // 8 KB
    __shared__ unsigned short Bs[128 * 32];   // 8 KB
    const int tid  = threadIdx.x;
    const int lane = tid & 63;
    const int wave = tid >> 6;
    const int qm   = lane & 15;
    const int quad = lane >> 4;
    const int m0 = blockIdx.y * 128;
    const int n0 = blockIdx.x * 128;
    const int wm = (wave >> 1) * 64;
    const int wn = (wave & 1) * 64;

    f32x4 acc[4][4];
#pragma unroll
    for (int i = 0; i < 4; i++)
#pragma unroll
        for (int j = 0; j < 4; j++) acc[i][j] = (f32x4){0.f, 0.f, 0.f, 0.f};

    const int r1 = tid >> 2;
    const int c1 = (((tid & 3) ^ ((r1 >> 1) & 3)) * 8);
    const unsigned short* Ag = A + (size_t)(m0 + r1) * K + c1;
    const unsigned short* Wg = W + (size_t)(n0 + r1) * K + c1;
    unsigned short* AsW = &As[wave * 512];
    unsigned short* BsW = &Bs[wave * 512];
    const int swq = ((qm >> 1) & 3) * 8;

    for (int kt = 0; kt < K; kt += 32) {
        async16(Ag,                  AsW);
        async16(Ag + (size_t)64 * K, AsW + 2048);
        async16(Wg,                  BsW);
        async16(Wg + (size_t)64 * K, BsW + 2048);
        Ag += 32; Wg += 32;
        __syncthreads();
        short8 af[4], bfr[4];
#pragma unroll
        for (int mi = 0; mi < 4; mi++)
            af[mi] = *(const short8*)&As[(wm + mi * 16 + qm) * 32 + (quad * 8 ^ swq)];
#pragma unroll
        for (int ni = 0; ni < 4; ni++)
            bfr[ni] = *(const short8*)&Bs[(wn + ni * 16 + qm) * 32 + (quad * 8 ^ swq)];
#pragma unroll
        for (int mi = 0; mi < 4; mi++)
#pragma unroll
            for (int ni = 0; ni < 4; ni++)
                acc[mi][ni] = __builtin_amdgcn_mfma_f32_16x16x32_bf16(af[mi], bfr[ni], acc[mi][ni], 0, 0, 0);
        __syncthreads();
    }
#pragma unroll
    for (int mi = 0; mi < 4; mi++) {
#pragma unroll
        for (int r = 0; r < 4; r++) {
            int row = m0 + wm + mi * 16 + quad * 4 + r;
            if (BF16OUT) {
                unsigned short* Crow = (unsigned short*)Cv + (size_t)row * N + n0 + wn + qm;
#pragma unroll
                for (int ni = 0; ni < 4; ni++) Crow[ni * 16] = f2bf(acc[mi][ni][r]);
            } else {
                float* Crow = (float*)Cv + (size_t)row * N + n0 + wn + qm;
#pragma unroll
                for (int ni = 0; ni < 4; ni++) Crow[ni * 16] = acc[mi][ni][r];
            }
        }
    }
}

// ---------------- postprocess: rmsnorm + rope + gain + attn-scale (bf16 in/out) -------
// q pre-scale includes log2(e) so attention softmax uses exp2 directly.
__global__ __launch_bounds__(256) void postproc(const unsigned short* __restrict__ qkvb,
                                                const float* __restrict__ gain,
                                                unsigned short* __restrict__ qb,
                                                unsigned short* __restrict__ kb) {
    const int m = blockIdx.x;          // 0..4095
    const int b = m >> 11;
    const int s = m & 2047;
    const int wave = threadIdx.x >> 6;
    const int lane = threadIdx.x & 63;
    const unsigned short* row = qkvb + (size_t)m * QKVN;
    // inv_freq = 10000^(-lane/64) = exp2(-lane * log2(10000)/64)
    float inv_freq = __builtin_amdgcn_exp2f(-(float)lane * 0.20761871f);
    float ang = (float)s * inv_freq;
    float sn, cs;
    sincosf(ang, &sn, &cs);
    const float scale = 0.12751744f;   // (1/sqrt(128)) * log2(e)
    for (int u = wave; u < 20; u += 4) {       // 16 q heads + 4 k heads
        int off = (u < 16) ? (u * HD) : (D_MODEL + (u - 16) * HD);
        float x1 = bf2f(row[off + lane]);
        float x2 = bf2f(row[off + 64 + lane]);
        float ss = x1 * x1 + x2 * x2;
        ss += __shfl_xor(ss, 1);  ss += __shfl_xor(ss, 2);  ss += __shfl_xor(ss, 4);
        ss += __shfl_xor(ss, 8);  ss += __shfl_xor(ss, 16); ss += __shfl_xor(ss, 32);
        float rs = rsqrtf(ss * (1.0f / 128.0f) + 1.1920929e-07f);
        float a1 = x1 * rs, a2 = x2 * rs;
        float o1 = a1 * cs + a2 * sn;
        float o2 = -a1 * sn + a2 * cs;
        if (u < 16) {
            float g = gain[u] * scale;
            o1 *= g; o2 *= g;
            size_t base = ((size_t)(b * NH + u) * SEQ + s) * HD;
            qb[base + lane] = f2bf(o1);
            qb[base + 64 + lane] = f2bf(o2);
        } else {
            size_t base = ((size_t)(b * NKV + (u - 16)) * SEQ + s) * HD;
            kb[base + lane] = f2bf(o1);
            kb[base + 64 + lane] = f2bf(o2);
        }
    }
}

// ---------------- V transpose: qkv bf16 -> vt bf16 [b][hk][d][s] ----------------
__global__ __launch_bounds__(256) void vtrans(const unsigned short* __restrict__ qkvb,
                                              unsigned short* __restrict__ vt) {
    __shared__ unsigned short tile[64][68];  // 68: keeps 8B-aligned ushort4 rows
    int idx = blockIdx.x;
    int st = idx & 31;
    int dt = (idx >> 5) & 1;
    int hk = (idx >> 6) & 3;
    int b  = idx >> 8;
    int t  = threadIdx.x;
    int cr = t >> 4;         // 0..15
    int cc = (t & 15) * 4;   // 0..60
#pragma unroll
    for (int j = 0; j < 4; j++) {
        int row = j * 16 + cr;  // s-local
        const unsigned short* src = qkvb + (size_t)(b * SEQ + st * 64 + row) * QKVN
                                  + (D_MODEL + KVD) + hk * HD + dt * 64 + cc;
        *(ushort4*)&tile[row][cc] = *(const ushort4*)src;
    }
    __syncthreads();
#pragma unroll
    for (int j = 0; j < 4; j++) {
        int drow = j * 16 + cr;  // d-local
        ushort4 ov;
        ov.x = tile[cc + 0][drow];
        ov.y = tile[cc + 1][drow];
        ov.z = tile[cc + 2][drow];
        ov.w = tile[cc + 3][drow];
        *(ushort4*)(vt + (size_t)((b * NKV + hk) * HD + dt * 64 + drow) * SEQ + st * 64 + cc) = ov;
    }
}

// ---------------- flash attention v4: fixed-cap softmax (no online max/rescale) -------
// |score_log2| <= 128*scale*|gain| <= 16.4|gain|  (rmsnorm'd q,k + Cauchy-Schwarz),
// so p = exp2(s - 17|gain|) never overflows and softmax is shift-invariant -> exact.
// Inner loop has ZERO cross-lane ops; l reduced once at the end.
__global__ __launch_bounds__(256, 4) void attn(const unsigned short* __restrict__ qb,
                                               const unsigned short* __restrict__ kb,
                                               const unsigned short* __restrict__ vt,
                                               const float* __restrict__ gain,
                                               unsigned short* __restrict__ y) {
    __shared__ unsigned short Ks[4096];      // [c][r][j^swz(r)] (8 KB)
    __shared__ unsigned short Vs[4096];      // [d][s^swz(d)]   (8 KB)
    __shared__ unsigned short plds[4][640];  // wave-private P, 16 rows x 40 (padded)
    const int tid  = threadIdx.x;
    const int lane = tid & 63;
    const int wave = tid >> 6;
    const int bh   = blockIdx.x & 31;
    const int g  = blockIdx.x >> 5;
    const int gg = g & 7;
    const int gs = g >> 3;
    const int qt64 = (gs == 0) ? gg : (gs == 1) ? (31 - gg) : (gs == 2) ? (8 + gg) : (23 - gg);
    const int h = bh & 15;
    const int b = bh >> 4;
    const int qm   = lane & 15;
    const int quad = lane >> 4;
    const int q0    = qt64 * 64;
    const int qrow0 = q0 + wave * 16;
    const float M = 17.0f * fabsf(gain[h]);

    const unsigned short* Qp = qb + (((size_t)(b * NH + h)) * SEQ + qrow0) * HD;
    const unsigned short* Kp = kb + ((size_t)(b * NKV + (h >> 2))) * SEQ * HD;
    const unsigned short* Vp = vt + ((size_t)(b * NKV + (h >> 2))) * HD * SEQ;

    short8 qf[4];
#pragma unroll
    for (int c = 0; c < 4; c++)
        qf[c] = *(const short8*)(Qp + qm * HD + c * 32 + quad * 8);

    f32x4 o[8];
#pragma unroll
    for (int t = 0; t < 8; t++) o[t] = (f32x4){0.f, 0.f, 0.f, 0.f};
    float lr[4] = {0.f, 0.f, 0.f, 0.f};

    const int sr  = (tid & 127) >> 2;                        // K row 0..31
    const int skc = ((tid & 3) ^ ((sr >> 1) & 3)) * 8;
    const unsigned short* KsA = Kp + sr * HD + (tid >> 7) * 32 + skc;
    const int vd  = tid >> 2;                                // V d-row 0..63
    const int svc = ((tid & 3) ^ ((vd >> 1) & 3)) * 8;
    const unsigned short* VsA = Vp + (size_t)vd * SEQ + svc;
    char* KsB = (char*)Ks + wave * 1024;
    char* VsB = (char*)Vs + wave * 1024;
    unsigned short* P = &plds[wave][0];
    const int swq = ((qm >> 1) & 3) * 8;

    const int kvend = q0 + 64;
    for (int kv0 = 0; kv0 < kvend; kv0 += 32) {
        async16(KsA,            KsB);
        async16(KsA + 64,       KsB + 4096);
        async16(VsA,            VsB);
        async16(VsA + 64 * SEQ, VsB + 4096);
        KsA += 32 * HD;
        VsA += 32;
        __syncthreads();
        if (kv0 <= qrow0 + 15) {   // wave-uniform: skip fully-masked tiles
            f32x4 s0 = (f32x4){0.f, 0.f, 0.f, 0.f};
            f32x4 s1 = (f32x4){0.f, 0.f, 0.f, 0.f};
#pragma unroll
            for (int c = 0; c < 4; c++) {
                short8 k0 = *(const short8*)&Ks[c * 1024 + qm * 32 + (quad * 8 ^ swq)];
                short8 k1 = *(const short8*)&Ks[c * 1024 + (16 + qm) * 32 + (quad * 8 ^ swq)];
                s0 = __builtin_amdgcn_mfma_f32_16x16x32_bf16(qf[c], k0, s0, 0, 0, 0);
                s1 = __builtin_amdgcn_mfma_f32_16x16x32_bf16(qf[c], k1, s1, 0, 0, 0);
            }
            if (kv0 + 31 > qrow0) {
#pragma unroll
                for (int r = 0; r < 4; r++) {
                    int qg = qrow0 + quad * 4 + r;
                    if (kv0 + qm > qg)      s0[r] = -3.0e38f;
                    if (kv0 + 16 + qm > qg) s1[r] = -3.0e38f;
                }
            }
            float p0[4], p1[4];
#pragma unroll
            for (int r = 0; r < 4; r++) {
                p0[r] = __builtin_amdgcn_exp2f(s0[r] - M);
                p1[r] = __builtin_amdgcn_exp2f(s1[r] - M);
                lr[r] += p0[r] + p1[r];
            }
#pragma unroll
            for (int r = 0; r < 4; r++) {
                P[(quad * 4 + r) * 40 + qm]      = f2bf_pos(p0[r]);
                P[(quad * 4 + r) * 40 + 16 + qm] = f2bf_pos(p1[r]);
            }
            short8 pa = *(const short8*)&P[qm * 40 + quad * 8];
#pragma unroll
            for (int t = 0; t < 8; t++) {
                short8 vf = *(const short8*)&Vs[(t * 16 + qm) * 32 + (quad * 8 ^ swq)];
                o[t] = __builtin_amdgcn_mfma_f32_16x16x32_bf16(pa, vf, o[t], 0, 0, 0);
            }
        }
        __syncthreads();
    }
    // reduce l across the 16 kv-lanes (qm) once
    float rl[4];
#pragma unroll
    for (int r = 0; r < 4; r++) {
        float l = lr[r];
        l += __shfl_xor(l, 1);
        l += __shfl_xor(l, 2);
        l += __shfl_xor(l, 4);
        l += __shfl_xor(l, 8);
        rl[r] = 1.0f / l;
    }
#pragma unroll
    for (int t = 0; t < 8; t++) {
#pragma unroll
        for (int r = 0; r < 4; r++) {
            size_t row = (size_t)(b * SEQ + qrow0 + quad * 4 + r);
            y[row * D_MODEL + h * HD + t * 16 + qm] = f2bf(o[t][r] * rl[r]);
        }
    }
}

extern "C" void kernel_launch(void* const* d_in, const int* in_sizes, int n_in,
                              void* d_out, int out_size, void* d_ws, size_t ws_size,
                              hipStream_t stream) {
    const float* x  = (const float*)d_in[0];
    const float* Wq = (const float*)d_in[1];
    const float* Wk = (const float*)d_in[2];
    const float* Wv = (const float*)d_in[3];
    const float* Wp = (const float*)d_in[4];
    const float* qg = (const float*)d_in[5];

    char* ws = (char*)d_ws;
    unsigned short* xb   = (unsigned short*)(ws + 0);          // 16 MB (reused as y)
    unsigned short* wqkv = (unsigned short*)(ws + 16777216);   // 12 MB
    unsigned short* wp   = (unsigned short*)(ws + 29360128);   // 8 MB
    unsigned short* qkvb = (unsigned short*)(ws + 37748736);   // 25 MB (bf16 now)
    unsigned short* qbuf = (unsigned short*)(ws + 88080384);   // 16 MB
    unsigned short* kbuf = (unsigned short*)(ws + 104857600);  // 4 MB
    unsigned short* vtb  = (unsigned short*)(ws + 109051904);  // 4 MB
    unsigned short* y    = xb;                                 // alias: xb dead after GEMM1

    cast_all<<<18432, 256, 0, stream>>>(x, Wq, Wk, Wv, Wp, xb, wqkv, wp);

    gemm_bt<true><<<dim3(24, 32), 256, 0, stream>>>(xb, wqkv, qkvb, MROWS, QKVN, D_MODEL);
    postproc<<<MROWS, 256, 0, stream>>>(qkvb, qg, qbuf, kbuf);
    vtrans<<<512, 256, 0, stream>>>(qkvb, vtb);
    attn<<<1024, 256, 0, stream>>>(qbuf, kbuf, vtb, qg, y);
    gemm_bt<false><<<dim3(16, 32), 256, 0, stream>>>(y, wp, (float*)d_out, MROWS, D_MODEL, D_MODEL);
}

// Round 5
// 298.470 us; speedup vs baseline: 2.3962x; 1.0688x over previous
//
#include <hip/hip_runtime.h>

#define D_MODEL 2048
#define SEQ 2048
#define BATCH 2
#define NH 16
#define NKV 4
#define HD 128
#define KVD (NKV * HD)              // 512
#define QKVN (D_MODEL + 2 * KVD)    // 3072
#define MROWS (BATCH * SEQ)         // 4096

typedef __attribute__((ext_vector_type(8))) short short8;
typedef __attribute__((ext_vector_type(4))) float f32x4;

__device__ __forceinline__ unsigned short f2bf(float f) {
    union { float f; unsigned int u; } v; v.f = f;
    unsigned int r = (v.u + 0x7FFFu + ((v.u >> 16) & 1u)) >> 16;
    return (unsigned short)r;
}

// round-to-nearest for NON-NEGATIVE floats only (2 ops)
__device__ __forceinline__ unsigned short f2bf_pos(float f) {
    union { float f; unsigned int u; } v; v.f = f;
    return (unsigned short)((v.u + 0x8000u) >> 16);
}

__device__ __forceinline__ float bf2f(unsigned short u) {
    union { float f; unsigned int i; } v; v.i = ((unsigned int)u) << 16;
    return v.f;
}

__device__ __forceinline__ void async16(const void* g, void* l) {
    __builtin_amdgcn_global_load_lds((const __attribute__((address_space(1))) void*)g,
                                     (__attribute__((address_space(3))) void*)l, 16, 0, 0);
}

// ---------------- merged f32 -> bf16 cast for x, Wq, Wk, Wv, Wp (one launch) ----------
__global__ __launch_bounds__(256) void cast_all(const float* __restrict__ x,
                                                const float* __restrict__ wq,
                                                const float* __restrict__ wk,
                                                const float* __restrict__ wv,
                                                const float* __restrict__ wp,
                                                unsigned short* __restrict__ xb,
                                                unsigned short* __restrict__ wqkv,
                                                unsigned short* __restrict__ wpb) {
    int i = blockIdx.x * 256 + threadIdx.x;  // float4 index, regions block-aligned
    const float4* s; ushort4* d; int j;
    if (i < 2097152)      { s = (const float4*)x;  d = (ushort4*)xb;             j = i; }
    else if (i < 3145728) { s = (const float4*)wq; d = (ushort4*)wqkv;           j = i - 2097152; }
    else if (i < 3407872) { s = (const float4*)wk; d = (ushort4*)wqkv + 1048576; j = i - 3145728; }
    else if (i < 3670016) { s = (const float4*)wv; d = (ushort4*)wqkv + 1310720; j = i - 3407872; }
    else                  { s = (const float4*)wp; d = (ushort4*)wpb;            j = i - 3670016; }
    float4 v = s[j];
    ushort4 o;
    o.x = f2bf(v.x); o.y = f2bf(v.y); o.z = f2bf(v.z); o.w = f2bf(v.w);
    d[j] = o;
}

// ---------------- GEMM1 fused: qkv = x @ Wqkv^T, then rmsnorm/rope/gain (q,k) or
// transpose (v) in-epilogue. Column tile (128) == one head. ----------------
__global__ __launch_bounds__(256) void gemm_qkv(const unsigned short* __restrict__ A,
                                                const unsigned short* __restrict__ W,
                                                const float* __restrict__ gain,
                                                unsigned short* __restrict__ qbuf,
                                                unsigned short* __restrict__ kbuf,
                                                unsigned short* __restrict__ vtb) {
    __shared__ unsigned short smem[128 * 137];   // 35 KB; reused: staging then out-tile
    unsigned short* As = smem;                   // 4096 ushorts (8 KB)
    unsigned short* Bs = smem + 4096;            // 4096 ushorts (8 KB)
    unsigned short* tile = smem;                 // 128 x 137
    const int K = D_MODEL;
    const int tid  = threadIdx.x;
    const int lane = tid & 63;
    const int wave = tid >> 6;
    const int qm   = lane & 15;
    const int quad = lane >> 4;
    const int m0 = blockIdx.y * 128;
    const int bx = blockIdx.x;
    const int n0 = bx * 128;
    const int wm = (wave >> 1) * 64;
    const int wn = (wave & 1) * 64;

    f32x4 acc[4][4];
#pragma unroll
    for (int i = 0; i < 4; i++)
#pragma unroll
        for (int j = 0; j < 4; j++) acc[i][j] = (f32x4){0.f, 0.f, 0.f, 0.f};

    const int r1 = tid >> 2;
    const int c1 = (((tid & 3) ^ ((r1 >> 1) & 3)) * 8);
    const unsigned short* Ag = A + (size_t)(m0 + r1) * K + c1;
    const unsigned short* Wg = W + (size_t)(n0 + r1) * K + c1;
    unsigned short* AsW = &As[wave * 512];
    unsigned short* BsW = &Bs[wave * 512];
    const int swq = ((qm >> 1) & 3) * 8;

    for (int kt = 0; kt < K; kt += 32) {
        async16(Ag,                  AsW);
        async16(Ag + (size_t)64 * K, AsW + 2048);
        async16(Wg,                  BsW);
        async16(Wg + (size_t)64 * K, BsW + 2048);
        Ag += 32; Wg += 32;
        __syncthreads();
        short8 af[4], bfr[4];
#pragma unroll
        for (int mi = 0; mi < 4; mi++)
            af[mi] = *(const short8*)&As[(wm + mi * 16 + qm) * 32 + (quad * 8 ^ swq)];
#pragma unroll
        for (int ni = 0; ni < 4; ni++)
            bfr[ni] = *(const short8*)&Bs[(wn + ni * 16 + qm) * 32 + (quad * 8 ^ swq)];
#pragma unroll
        for (int mi = 0; mi < 4; mi++)
#pragma unroll
            for (int ni = 0; ni < 4; ni++)
                acc[mi][ni] = __builtin_amdgcn_mfma_f32_16x16x32_bf16(af[mi], bfr[ni], acc[mi][ni], 0, 0, 0);
        __syncthreads();
    }

    // dump acc (bf16) into the out-tile (stride 137 breaks bank alignment)
#pragma unroll
    for (int mi = 0; mi < 4; mi++)
#pragma unroll
        for (int r = 0; r < 4; r++) {
            int row = wm + mi * 16 + quad * 4 + r;
#pragma unroll
            for (int ni = 0; ni < 4; ni++)
                tile[row * 137 + wn + ni * 16 + qm] = f2bf(acc[mi][ni][r]);
        }
    __syncthreads();

    const int s_base = m0 & 2047;   // m0 is 128-aligned, batch doesn't split a tile
    const int bb = m0 >> 11;
    if (bx < 20) {
        // q head (bx<16) or k head (bx-16): rmsnorm + rope (+ gain*scale for q)
        const bool isq = bx < 16;
        const float g = isq ? gain[bx] * 0.12751744f : 1.0f;  // (1/sqrt(128))*log2e folded
        unsigned short* dst = isq
            ? qbuf + ((size_t)(bb * NH + bx) * SEQ + s_base) * HD
            : kbuf + ((size_t)(bb * NKV + (bx - 16)) * SEQ + s_base) * HD;
        const float inv_freq = __builtin_amdgcn_exp2f(-(float)lane * 0.20761871f);
        for (int rr = 0; rr < 32; rr++) {
            int row = wave * 32 + rr;
            float x1 = bf2f(tile[row * 137 + lane]);
            float x2 = bf2f(tile[row * 137 + 64 + lane]);
            float ss = x1 * x1 + x2 * x2;
            ss += __shfl_xor(ss, 1);  ss += __shfl_xor(ss, 2);  ss += __shfl_xor(ss, 4);
            ss += __shfl_xor(ss, 8);  ss += __shfl_xor(ss, 16); ss += __shfl_xor(ss, 32);
            float rs = rsqrtf(ss * (1.0f / 128.0f) + 1.1920929e-07f);
            float ang = (float)(s_base + row) * inv_freq;
            float sn, cs;
            sincosf(ang, &sn, &cs);
            float a1 = x1 * rs, a2 = x2 * rs;
            float o1 = (a1 * cs + a2 * sn) * g;
            float o2 = (a2 * cs - a1 * sn) * g;
            dst[(size_t)row * HD + lane]      = f2bf(o1);
            dst[(size_t)row * HD + 64 + lane] = f2bf(o2);
        }
    } else {
        // v head: write transposed vt[b][hk][d][s]
        const int hk = bx - 20;
        unsigned short* dst = vtb + ((size_t)(bb * NKV + hk) * HD) * SEQ + s_base;
        const int sc = (tid & 31) * 4;
        const int d0 = tid >> 5;
#pragma unroll
        for (int i = 0; i < 16; i++) {
            int d = d0 + 8 * i;
            ushort4 ov;
            ov.x = tile[(sc + 0) * 137 + d];
            ov.y = tile[(sc + 1) * 137 + d];
            ov.z = tile[(sc + 2) * 137 + d];
            ov.w = tile[(sc + 3) * 137 + d];
            *(ushort4*)(dst + (size_t)d * SEQ + sc) = ov;
        }
    }
}

// ---------------- GEMM2: C[M,N] = A[M,K] * W[N,K]^T  (bf16 in, fp32 out) --------------
__global__ __launch_bounds__(256) void gemm_bt(const unsigned short* __restrict__ A,
                                               const unsigned short* __restrict__ W,
                                               float* __restrict__ C, int M, int N, int K) {
    __shared__ unsigned short As[128 * 32];
    __shared__ unsigned short Bs[128 * 32];
    const int tid  = threadIdx.x;
    const int lane = tid & 63;
    const int wave = tid >> 6;
    const int qm   = lane & 15;
    const int quad = lane >> 4;
    const int m0 = blockIdx.y * 128;
    const int n0 = blockIdx.x * 128;
    const int wm = (wave >> 1) * 64;
    const int wn = (wave & 1) * 64;

    f32x4 acc[4][4];
#pragma unroll
    for (int i = 0; i < 4; i++)
#pragma unroll
        for (int j = 0; j < 4; j++) acc[i][j] = (f32x4){0.f, 0.f, 0.f, 0.f};

    const int r1 = tid >> 2;
    const int c1 = (((tid & 3) ^ ((r1 >> 1) & 3)) * 8);
    const unsigned short* Ag = A + (size_t)(m0 + r1) * K + c1;
    const unsigned short* Wg = W + (size_t)(n0 + r1) * K + c1;
    unsigned short* AsW = &As[wave * 512];
    unsigned short* BsW = &Bs[wave * 512];
    const int swq = ((qm >> 1) & 3) * 8;

    for (int kt = 0; kt < K; kt += 32) {
        async16(Ag,                  AsW);
        async16(Ag + (size_t)64 * K, AsW + 2048);
        async16(Wg,                  BsW);
        async16(Wg + (size_t)64 * K, BsW + 2048);
        Ag += 32; Wg += 32;
        __syncthreads();
        short8 af[4], bfr[4];
#pragma unroll
        for (int mi = 0; mi < 4; mi++)
            af[mi] = *(const short8*)&As[(wm + mi * 16 + qm) * 32 + (quad * 8 ^ swq)];
#pragma unroll
        for (int ni = 0; ni < 4; ni++)
            bfr[ni] = *(const short8*)&Bs[(wn + ni * 16 + qm) * 32 + (quad * 8 ^ swq)];
#pragma unroll
        for (int mi = 0; mi < 4; mi++)
#pragma unroll
            for (int ni = 0; ni < 4; ni++)
                acc[mi][ni] = __builtin_amdgcn_mfma_f32_16x16x32_bf16(af[mi], bfr[ni], acc[mi][ni], 0, 0, 0);
        __syncthreads();
    }
#pragma unroll
    for (int mi = 0; mi < 4; mi++) {
#pragma unroll
        for (int r = 0; r < 4; r++) {
            int row = m0 + wm + mi * 16 + quad * 4 + r;
            float* Crow = C + (size_t)row * N + n0 + wn + qm;
#pragma unroll
            for (int ni = 0; ni < 4; ni++) Crow[ni * 16] = acc[mi][ni][r];
        }
    }
}

// ---------------- flash attention v5: BKV=64 (half the barriers), fixed-cap softmax ---
// LDS exactly 40 KB -> 4 blocks/CU. XOR-swizzled K/V/P chunk layouts, zero pad.
__global__ __launch_bounds__(256, 4) void attn(const unsigned short* __restrict__ qb,
                                               const unsigned short* __restrict__ kb,
                                               const unsigned short* __restrict__ vt,
                                               const float* __restrict__ gain,
                                               unsigned short* __restrict__ y) {
    __shared__ unsigned short Ks[8192];      // 64 kv-rows x 128 d, swizzled (16 KB)
    __shared__ unsigned short Vs[8192];      // 128 d-rows x 64 s, swizzled (16 KB)
    __shared__ unsigned short plds[4][1024]; // wave-private P: 16 x 64, swizzled (8 KB)
    const int tid  = threadIdx.x;
    const int lane = tid & 63;
    const int wave = tid >> 6;
    const int bh   = blockIdx.x & 31;
    const int g4   = blockIdx.x >> 5;
    const int gg = g4 & 7;
    const int gs = g4 >> 3;
    const int qt64 = (gs == 0) ? gg : (gs == 1) ? (31 - gg) : (gs == 2) ? (8 + gg) : (23 - gg);
    const int h = bh & 15;
    const int b = bh >> 4;
    const int qm   = lane & 15;
    const int quad = lane >> 4;
    const int q0    = qt64 * 64;
    const int qrow0 = q0 + wave * 16;
    const float M = 17.0f * fabsf(gain[h]);

    const unsigned short* Qp = qb + (((size_t)(b * NH + h)) * SEQ + qrow0) * HD;
    const unsigned short* Kp = kb + ((size_t)(b * NKV + (h >> 2))) * SEQ * HD;
    const unsigned short* Vp = vt + ((size_t)(b * NKV + (h >> 2))) * HD * SEQ;

    short8 qf[4];
#pragma unroll
    for (int c = 0; c < 4; c++)
        qf[c] = *(const short8*)(Qp + qm * HD + c * 32 + quad * 8);

    f32x4 o[8];
#pragma unroll
    for (int t = 0; t < 8; t++) o[t] = (f32x4){0.f, 0.f, 0.f, 0.f};
    float lr[4] = {0.f, 0.f, 0.f, 0.f};

    // K staging: issue i covers rows 16i..16i+15; thread t -> row 16i+(t>>4),
    // global chunk (t&15)^(t>>4) (swizzle by row&15). LDS linear = i*2048 + t*8.
    const unsigned short* KsA = Kp + (size_t)(tid >> 4) * HD + (((tid & 15) ^ (tid >> 4)) & 15) * 8;
    // V staging: issue i covers d-rows 32i..32i+31; thread t -> d 32i+(t>>3),
    // global chunk (t&7)^((t>>3)&7). LDS linear = i*2048 + t*8.
    const unsigned short* VsA = Vp + (size_t)(tid >> 3) * SEQ + (((tid & 7) ^ ((tid >> 3) & 7)) * 8);
    char* KsB = (char*)Ks + wave * 1024;
    char* VsB = (char*)Vs + wave * 1024;
    unsigned short* P = &plds[wave][0];

    const int kvend = q0 + 64;
    for (int kv0 = 0; kv0 < kvend; kv0 += 64) {
#pragma unroll
        for (int i = 0; i < 4; i++) {
            async16(KsA + (size_t)(16 * i) * HD,  KsB + i * 4096);
            async16(VsA + (size_t)(32 * i) * SEQ, VsB + i * 4096);
        }
        KsA += (size_t)64 * HD;
        VsA += 64;
        __syncthreads();

        f32x4 s[4];
#pragma unroll
        for (int g = 0; g < 4; g++) s[g] = (f32x4){0.f, 0.f, 0.f, 0.f};
#pragma unroll
        for (int c = 0; c < 4; c++) {
#pragma unroll
            for (int g = 0; g < 4; g++) {
                short8 kf = *(const short8*)&Ks[(g * 16 + qm) * 128 + (((c * 4 + quad) ^ qm) * 8)];
                s[g] = __builtin_amdgcn_mfma_f32_16x16x32_bf16(qf[c], kf, s[g], 0, 0, 0);
            }
        }
        if (kv0 + 63 > qrow0) {   // final (diagonal) tile only
#pragma unroll
            for (int g = 0; g < 4; g++)
#pragma unroll
                for (int r = 0; r < 4; r++) {
                    int qg = qrow0 + quad * 4 + r;
                    if (kv0 + g * 16 + qm > qg) s[g][r] = -3.0e38f;
                }
        }
        float p[4][4];
#pragma unroll
        for (int g = 0; g < 4; g++)
#pragma unroll
            for (int r = 0; r < 4; r++) {
                p[g][r] = __builtin_amdgcn_exp2f(s[g][r] - M);
                lr[r] += p[g][r];
            }
        // P: C-layout -> A-layout, swizzled chunks (no pad, conflict-free read)
#pragma unroll
        for (int g = 0; g < 4; g++)
#pragma unroll
            for (int r = 0; r < 4; r++) {
                int rowp = quad * 4 + r;
                P[rowp * 64 + (((g * 2 + (qm >> 3)) ^ (rowp & 7)) * 8) + (qm & 7)] = f2bf_pos(p[g][r]);
            }
        short8 pa[2];
#pragma unroll
        for (int ka = 0; ka < 2; ka++)
            pa[ka] = *(const short8*)&P[qm * 64 + (((ka * 4 + quad) ^ (qm & 7)) * 8)];
#pragma unroll
        for (int t = 0; t < 8; t++) {
#pragma unroll
            for (int ka = 0; ka < 2; ka++) {
                short8 vf = *(const short8*)&Vs[(t * 16 + qm) * 64 + (((ka * 4 + quad) ^ (qm & 7)) * 8)];
                o[t] = __builtin_amdgcn_mfma_f32_16x16x32_bf16(pa[ka], vf, o[t], 0, 0, 0);
            }
        }
        __syncthreads();
    }
    float rl[4];
#pragma unroll
    for (int r = 0; r < 4; r++) {
        float l = lr[r];
        l += __shfl_xor(l, 1);
        l += __shfl_xor(l, 2);
        l += __shfl_xor(l, 4);
        l += __shfl_xor(l, 8);
        rl[r] = 1.0f / l;
    }
#pragma unroll
    for (int t = 0; t < 8; t++) {
#pragma unroll
        for (int r = 0; r < 4; r++) {
            size_t row = (size_t)(b * SEQ + qrow0 + quad * 4 + r);
            y[row * D_MODEL + h * HD + t * 16 + qm] = f2bf(o[t][r] * rl[r]);
        }
    }
}

extern "C" void kernel_launch(void* const* d_in, const int* in_sizes, int n_in,
                              void* d_out, int out_size, void* d_ws, size_t ws_size,
                              hipStream_t stream) {
    const float* x  = (const float*)d_in[0];
    const float* Wq = (const float*)d_in[1];
    const float* Wk = (const float*)d_in[2];
    const float* Wv = (const float*)d_in[3];
    const float* Wp = (const float*)d_in[4];
    const float* qg = (const float*)d_in[5];

    char* ws = (char*)d_ws;
    unsigned short* xb   = (unsigned short*)(ws + 0);          // 16 MB (reused as y)
    unsigned short* wqkv = (unsigned short*)(ws + 16777216);   // 12 MB
    unsigned short* wp   = (unsigned short*)(ws + 29360128);   // 8 MB
    unsigned short* qbuf = (unsigned short*)(ws + 37748736);   // 16 MB
    unsigned short* kbuf = (unsigned short*)(ws + 54525952);   // 4 MB
    unsigned short* vtb  = (unsigned short*)(ws + 58720256);   // 4 MB
    unsigned short* y    = xb;                                 // alias: xb dead after GEMM1

    cast_all<<<18432, 256, 0, stream>>>(x, Wq, Wk, Wv, Wp, xb, wqkv, wp);
    gemm_qkv<<<dim3(24, 32), 256, 0, stream>>>(xb, wqkv, qg, qbuf, kbuf, vtb);
    attn<<<1024, 256, 0, stream>>>(qbuf, kbuf, vtb, qg, y);
    gemm_bt<<<dim3(16, 32), 256, 0, stream>>>(y, wp, (float*)d_out, MROWS, D_MODEL, D_MODEL);
}